// Round 5
// baseline (540.426 us; speedup 1.0000x reference)
//
#include <hip/hip_runtime.h>
#include <math.h>

#define NB 32          // batch
#define NN 32          // max gt per image
#define NG (NB*NN)     // total gt records
#define NC 81          // classes
#define RSZ 416.0f
#define ROWS 4         // cell-anchor rows per thread (MLP)

// block layout of the fused loss kernel:
//   scale 0 (S=13): 1 chunk/image  -> blocks [0,32)
//   scale 1 (S=26): 2 chunks/image -> blocks [32,96)
//   scale 2 (S=52): 8 chunks/image -> blocks [96,352)
#define NPART 352

// bce(sigmoid(x), 1) = softplus(-x); bce(sigmoid(x), 0) = softplus(x)
__device__ __forceinline__ float softplusf(float x) {
    return fmaxf(x, 0.f) + log1pf(expf(-fabsf(x)));
}

__device__ __forceinline__ unsigned getbit(int c, unsigned b0, unsigned b1, unsigned b2) {
    unsigned w = (c < 32) ? b0 : (c < 64) ? b1 : b2;
    return (w >> (c & 31)) & 1u;
}

// -------------------------------------------------------------------------
// Kernel A: per-GT assignment, one thread per (b, n).
// JAX semantics: b_safe = where(assign, b, -1) with mode='drop' — negative
// indices WRAP before OOB handling, so -1 -> B-1 = 31. Every GT scatters at
// EVERY scale, into image b if assigned there, else image 31.
// meta[i*NG+g]: bits 0-5 cellx | 6-11 celly | 12-13 j | 14-20 cls
//               | 21-25 eb | 26 valid;  rect[(i*NG+g)*4] = {tx,ty,tw,th}
// -------------------------------------------------------------------------
__global__ __launch_bounds__(256) void yolo_assign(
    const float* __restrict__ gt_boxes, const int* __restrict__ gt_labels,
    const unsigned* __restrict__ gt_mask,
    const float* __restrict__ aw_l, const float* __restrict__ aw_m,
    const float* __restrict__ aw_s,
    int* __restrict__ meta, float* __restrict__ rect)
{
    int t = blockIdx.x * blockDim.x + threadIdx.x;
    if (t >= NG) return;
    int b = t / NN;

    // gt_mask storage detect (int32 {0,1} vs packed uint8 bools): branch-free
    // OR over 64 words (256 u8 bools @70% density -> P(miss) ~ 1e-50).
    unsigned det = 0;
    #pragma unroll
    for (int k = 0; k < 64; ++k) det |= gt_mask[k];
    bool u8 = (det & 0xFFFFFF00u) != 0;
    int valid = u8 ? (((const unsigned char*)gt_mask)[t] != 0)
                   : (gt_mask[t] != 0);

    const float* bx = gt_boxes + t * 4;
    float x1 = bx[0], y1 = bx[1], x2 = bx[2], y2 = bx[3];
    float cx0 = (x1 + x2) * 0.5f, cy0 = (y1 + y2) * 0.5f;
    float w0 = x2 - x1, h0 = y2 - y1;

    const float* anch[3] = { aw_l, aw_m, aw_s };
    const int    Ss[3]   = { 13, 26, 52 };

    // ---- pass 1: best scale via exact max-IoU (separable in x/y) --------
    float best_m = -1.f; int best = 0;
    for (int i = 0; i < 3; ++i) {
        int Si = Ss[i]; float S = (float)Si;
        float stride = RSZ / S;
        float cx = cx0 * S, cy = cy0 * S, w = w0 * S, h = h0 * S;
        float gx1 = cx - w * 0.5f, gy1 = cy - h * 0.5f;
        float gx2 = cx + w * 0.5f, gy2 = cy + h * 0.5f;
        float ag = (gx2 - gx1) * (gy2 - gy1);
        float m = 0.f;
        for (int a = 0; a < 3; ++a) {
            float aw = anch[i][a * 2 + 0] / stride;
            float ah = anch[i][a * 2 + 1] / stride;
            float aw2 = aw * 0.5f, ah2 = ah * 0.5f;
            float aa = aw * ah;
            float mox = 0.f, moy = 0.f;
            for (int c = 0; c < Si; ++c) {
                float ac = c + 0.5f;
                mox = fmaxf(mox, fminf(gx2, ac + aw2) - fmaxf(gx1, ac - aw2));
                moy = fmaxf(moy, fminf(gy2, ac + ah2) - fmaxf(gy1, ac - ah2));
            }
            float inter = mox * moy;
            m = fmaxf(m, inter / (ag + aa - inter));
        }
        if (m > best_m) { best_m = m; best = i; }   // first-max wins
    }

    int cls = gt_labels[t] + 1;
    cls = min(max(cls, 0), NC - 1);

    // ---- pass 2: per-scale record ---------------------------------------
    for (int i = 0; i < 3; ++i) {
        int Si = Ss[i]; float S = (float)Si;
        float stride = RSZ / S;
        float cx = cx0 * S, cy = cy0 * S, w = w0 * S, h = h0 * S;
        float gx1 = cx - w * 0.5f, gy1 = cy - h * 0.5f;
        float gx2 = cx + w * 0.5f, gy2 = cy + h * 0.5f;
        float ag = (gx2 - gx1) * (gy2 - gy1);

        int cellx = (int)floorf(cx); cellx = min(max(cellx, 0), Si - 1);
        int celly = (int)floorf(cy); celly = min(max(celly, 0), Si - 1);
        float acx = cellx + 0.5f, acy = celly + 0.5f;

        float biou = -1.f; int j = 0;
        for (int a = 0; a < 3; ++a) {
            float aw = anch[i][a * 2 + 0] / stride;
            float ah = anch[i][a * 2 + 1] / stride;
            float ox = fmaxf(0.f, fminf(gx2, acx + aw * 0.5f) - fmaxf(gx1, acx - aw * 0.5f));
            float oy = fmaxf(0.f, fminf(gy2, acy + ah * 0.5f) - fmaxf(gy1, acy - ah * 0.5f));
            float inter = ox * oy;
            float iou = inter / (ag + aw * ah - inter);
            if (iou > biou) { biou = iou; j = a; }  // first-max wins
        }

        float tx = cx - floorf(cx), ty = cy - floorf(cy);
        float awj = anch[i][j * 2 + 0] / stride;
        float ahj = anch[i][j * 2 + 1] / stride;
        float tw = logf(w / awj), th = logf(h / ahj);

        int eb = (valid && best == i) ? b : (NB - 1);  // -1 wraps to B-1
        meta[i * NG + t] = cellx | (celly << 6) | (j << 12) | (cls << 14)
                         | (eb << 21) | (valid ? (1 << 26) : 0);
        float* r = rect + (i * NG + t) * 4;
        r[0] = tx; r[1] = ty; r[2] = tw; r[3] = th;
    }
}

// -------------------------------------------------------------------------
// Fused per-scale loss body. Each thread handles ROWS cell-anchor rows
// (independent obj-logit loads issued up-front for MLP). Per-block partial
// sum is returned (reduced by caller); no atomics.
// -------------------------------------------------------------------------
template<int S>
__device__ __forceinline__ float loss_chunk(
    const float* __restrict__ pred, const float* __restrict__ anch,
    const float* __restrict__ gt_boxes,
    const int* __restrict__ ms, const float* __restrict__ rs,
    int b, int chunk,
    float (&s_g)[NN][5], int* s_valid, int* s_cm)
{
    constexpr int SS3 = S * S * 3;
    const float stride = RSZ / (float)S;

    bool wrapimg = (b == NB - 1);
    int ncand = wrapimg ? NG : NN;
    int cbase = wrapimg ? 0 : b * NN;

    for (int c = threadIdx.x; c < ncand; c += 256) s_cm[c] = ms[cbase + c];
    if (threadIdx.x < NN) {
        int n = threadIdx.x;
        const float* bxp = gt_boxes + (b * NN + n) * 4;
        float x1 = bxp[0], y1 = bxp[1], x2 = bxp[2], y2 = bxp[3];
        float Sf = (float)S;
        float cx = (x1 + x2) * 0.5f * Sf, cy = (y1 + y2) * 0.5f * Sf;
        float w = (x2 - x1) * Sf, h = (y2 - y1) * Sf;
        float gx1 = cx - w * 0.5f, gy1 = cy - h * 0.5f;
        float gx2 = cx + w * 0.5f, gy2 = cy + h * 0.5f;
        s_g[n][0] = gx1; s_g[n][1] = gy1; s_g[n][2] = gx2; s_g[n][3] = gy2;
        s_g[n][4] = (gx2 - gx1) * (gy2 - gy1);
        s_valid[n] = (ms[b * NN + n] >> 26) & 1;
    }
    __syncthreads();

    // anchors (grid units), registers via cached broadcast loads
    float aw0 = anch[0] / stride, ah0 = anch[1] / stride;
    float aw1 = anch[2] / stride, ah1 = anch[3] / stride;
    float aw2 = anch[4] / stride, ah2 = anch[5] / stride;

    int base = chunk * 256 * ROWS + threadIdx.x;

    // phase 1: wants + issue all obj-logit loads (independent -> MLP)
    unsigned want[ROWS];
    const float2* pp[ROWS];
    float2 v2r[ROWS];
    #pragma unroll
    for (int k = 0; k < ROWS; ++k) {
        int r = base + k * 256;
        if (r < SS3) {
            int j = r % 3, cx = (r / 3) % S, cy = r / (3 * S);
            want[k] = (unsigned)(cx | (cy << 6) | (j << 12) | (b << 21));
            pp[k] = (const float2*)(pred +
                ((size_t)((b * S + cy) * S + cx)) * (3 * (5 + NC)) + j * (5 + NC));
            v2r[k] = pp[k][2];           // (obj, cls0)
        } else {
            want[k] = 0xFFFFFFFFu;       // never matches (bits outside MASK)
            pp[k] = (const float2*)pred; // safe dummy, never dereferenced
            v2r[k] = make_float2(0.f, 0.f);
        }
    }

    // phase 2: single candidate scan, matched against all ROWS wants.
    // Last match wins for txy/twh; class one-hots union.
    const unsigned MASK = 0x3FFFu | (31u << 21);
    int win[ROWS];
    unsigned cb0[ROWS], cb1[ROWS], cb2[ROWS];
    #pragma unroll
    for (int k = 0; k < ROWS; ++k) { win[k] = -1; cb0[k] = cb1[k] = cb2[k] = 0u; }
    for (int c = 0; c < ncand; ++c) {
        int m = s_cm[c];
        unsigned mk = (unsigned)m & MASK;
        int cl = (m >> 14) & 127;
        unsigned bit = 1u << (cl & 31);
        unsigned w0 = (cl < 32) ? bit : 0u;
        unsigned w1 = (cl >= 32 && cl < 64) ? bit : 0u;
        unsigned w2 = (cl >= 64) ? bit : 0u;
        #pragma unroll
        for (int k = 0; k < ROWS; ++k) {
            if (mk == want[k]) { win[k] = c; cb0[k] |= w0; cb1[k] |= w1; cb2[k] |= w2; }
        }
    }

    // phase 3: per-row loss
    float acc = 0.f;
    #pragma unroll
    for (int k = 0; k < ROWS; ++k) {
        int r = base + k * 256;
        if (r >= SS3) continue;
        int j = r % 3;
        float pobj = v2r[k].x;
        if (win[k] >= 0) {
            const float* tr = rs + (size_t)(cbase + win[k]) * 4;
            const float2* p2 = pp[k];
            float2 v0 = p2[0], v1 = p2[1];
            float sx = 1.f / (1.f + expf(-v0.x));
            float sy = 1.f / (1.f + expf(-v0.y));
            float dx = sx - tr[0], dy = sy - tr[1];
            float dw = v1.x - tr[2], dh = v1.y - tr[3];
            float xy_l  = 0.5f * (dx * dx + dy * dy);
            float wh_l  = 0.5f * (dw * dw + dh * dh);
            float obj_l = softplusf(-pobj);
            float cls_l = (cb0[k] & 1u) ? softplusf(-v2r[k].y) : softplusf(v2r[k].y);
            #pragma unroll 1
            for (int q = 3; q < 43; ++q) {
                float2 v = p2[q];
                int c0 = 2 * q - 5, c1 = 2 * q - 4;
                cls_l += getbit(c0, cb0[k], cb1[k], cb2[k]) ? softplusf(-v.x) : softplusf(v.x);
                cls_l += getbit(c1, cb0[k], cb1[k], cb2[k]) ? softplusf(-v.y) : softplusf(v.y);
            }
            acc += (5.f * (xy_l + wh_l) + obj_l + cls_l) * (1.f / NB);
        } else {
            float aw = (j == 0) ? aw0 : (j == 1) ? aw1 : aw2;
            float ah = (j == 0) ? ah0 : (j == 1) ? ah1 : ah2;
            int cx = (r / 3) % S, cy = r / (3 * S);
            float acx = cx + 0.5f, acy = cy + 0.5f;
            float ax1 = acx - aw * 0.5f, ax2 = acx + aw * 0.5f;
            float ay1 = acy - ah * 0.5f, ay2 = acy + ah * 0.5f;
            float aa = aw * ah;
            float miou = 0.f;
            for (int n = 0; n < NN; ++n) {
                if (!s_valid[n]) continue;
                float ox = fmaxf(0.f, fminf(s_g[n][2], ax2) - fmaxf(s_g[n][0], ax1));
                float oy = fmaxf(0.f, fminf(s_g[n][3], ay2) - fmaxf(s_g[n][1], ay1));
                float inter = ox * oy;
                miou = fmaxf(miou, inter / (s_g[n][4] + aa - inter));
            }
            float ignore = (miou < 0.5f) ? 1.f : 0.f;
            acc += 0.5f * ignore * softplusf(pobj) * (1.f / NB);
        }
    }
    return acc;
}

// -------------------------------------------------------------------------
// Fused loss kernel: all 3 scales in one launch; per-block partial stores.
// -------------------------------------------------------------------------
__global__ __launch_bounds__(256) void yolo_loss_all(
    const float* __restrict__ pred13, const float* __restrict__ pred26,
    const float* __restrict__ pred52, const float* __restrict__ gt_boxes,
    const float* __restrict__ aw_l, const float* __restrict__ aw_m,
    const float* __restrict__ aw_s,
    const int* __restrict__ meta, const float* __restrict__ rect,
    float* __restrict__ partial)
{
    __shared__ float s_g[NN][5];
    __shared__ int   s_valid[NN];
    __shared__ int   s_cm[NG];
    __shared__ float s_red[256];

    int bx = blockIdx.x;
    float acc;
    if (bx < 32) {
        acc = loss_chunk<13>(pred13, aw_l, gt_boxes, meta, rect,
                             bx, 0, s_g, s_valid, s_cm);
    } else if (bx < 96) {
        int l = bx - 32;
        acc = loss_chunk<26>(pred26, aw_m, gt_boxes, meta + NG,
                             rect + (size_t)NG * 4,
                             l >> 1, l & 1, s_g, s_valid, s_cm);
    } else {
        int l = bx - 96;
        acc = loss_chunk<52>(pred52, aw_s, gt_boxes, meta + 2 * NG,
                             rect + (size_t)2 * NG * 4,
                             l >> 3, l & 7, s_g, s_valid, s_cm);
    }

    s_red[threadIdx.x] = acc;
    __syncthreads();
    for (int o = 128; o > 0; o >>= 1) {
        if (threadIdx.x < o) s_red[threadIdx.x] += s_red[threadIdx.x + o];
        __syncthreads();
    }
    if (threadIdx.x == 0) partial[bx] = s_red[0];
}

__global__ __launch_bounds__(256) void yolo_finalize(
    const float* __restrict__ partial, float* __restrict__ out)
{
    __shared__ float s[256];
    float a = 0.f;
    for (int i = threadIdx.x; i < NPART; i += 256) a += partial[i];
    s[threadIdx.x] = a;
    __syncthreads();
    for (int o = 128; o > 0; o >>= 1) {
        if (threadIdx.x < o) s[threadIdx.x] += s[threadIdx.x + o];
        __syncthreads();
    }
    if (threadIdx.x == 0) out[0] = s[0];
}

extern "C" void kernel_launch(void* const* d_in, const int* in_sizes, int n_in,
                              void* d_out, int out_size, void* d_ws, size_t ws_size,
                              hipStream_t stream)
{
    const float*    pred_l    = (const float*)d_in[0];   // S=13
    const float*    pred_m    = (const float*)d_in[1];   // S=26
    const float*    pred_s    = (const float*)d_in[2];   // S=52
    const float*    gt_boxes  = (const float*)d_in[3];
    const int*      gt_labels = (const int*)d_in[4];
    const unsigned* gt_mask   = (const unsigned*)d_in[5];
    const float*    aw_l      = (const float*)d_in[6];
    const float*    aw_m      = (const float*)d_in[7];
    const float*    aw_s      = (const float*)d_in[8];

    int*   meta    = (int*)d_ws;                                        // 3*NG ints
    float* rect    = (float*)((char*)d_ws + 3 * NG * sizeof(int));      // 3*NG*4 f32
    float* partial = (float*)((char*)d_ws + 3 * NG * sizeof(int)
                                          + 3 * NG * 4 * sizeof(float)); // NPART f32

    yolo_assign<<<dim3((NG + 255) / 256), 256, 0, stream>>>(
        gt_boxes, gt_labels, gt_mask, aw_l, aw_m, aw_s, meta, rect);

    yolo_loss_all<<<dim3(NPART), 256, 0, stream>>>(
        pred_l, pred_m, pred_s, gt_boxes, aw_l, aw_m, aw_s, meta, rect, partial);

    yolo_finalize<<<dim3(1), 256, 0, stream>>>(partial, (float*)d_out);
}

// Round 7
// 316.620 us; speedup vs baseline: 1.7069x; 1.7069x over previous
//
#include <hip/hip_runtime.h>
#include <math.h>

#define NB 32          // batch
#define NN 32          // max gt per image
#define NG (NB*NN)     // total gt records
#define NC 81          // classes
#define RSZ 416.0f

// fused loss kernel block layout (ROWS=1, 256 rows per block):
//   S=13: 2 chunks/image  -> blocks [0,64)
//   S=26: 8 chunks/image  -> blocks [64,320)
//   S=52: 32 chunks/image -> blocks [320,1344)
#define NPART 1344

// bce(sigmoid(x), 1) = softplus(-x); bce(sigmoid(x), 0) = softplus(x)
__device__ __forceinline__ float softplusf(float x) {
    return fmaxf(x, 0.f) + log1pf(expf(-fabsf(x)));
}

__device__ __forceinline__ unsigned getbit(int c, unsigned b0, unsigned b1, unsigned b2) {
    unsigned w = (c < 32) ? b0 : (c < 64) ? b1 : b2;
    return (w >> (c & 31)) & 1u;
}

// -------------------------------------------------------------------------
// Kernel A: per-GT assignment, one thread per (b, n).
// JAX semantics: b_safe = where(assign, b, -1) with mode='drop' — negative
// indices WRAP before OOB handling, so -1 -> B-1 = 31. Every GT scatters at
// EVERY scale, into image b if assigned there, else image 31.
// meta[i*NG+g]: bits 0-5 cellx | 6-11 celly | 12-13 j | 14-20 cls
//               | 21-25 eb | 26 valid;  rect[(i*NG+g)*4] = {tx,ty,tw,th}
// -------------------------------------------------------------------------
__global__ __launch_bounds__(256) void yolo_assign(
    const float* __restrict__ gt_boxes, const int* __restrict__ gt_labels,
    const unsigned* __restrict__ gt_mask,
    const float* __restrict__ aw_l, const float* __restrict__ aw_m,
    const float* __restrict__ aw_s,
    int* __restrict__ meta, float* __restrict__ rect)
{
    int t = blockIdx.x * blockDim.x + threadIdx.x;
    if (t >= NG) return;
    int b = t / NN;

    // gt_mask storage detect (int32 {0,1} vs packed uint8 bools): branch-free
    // OR over 64 words (256 u8 bools @70% density -> P(miss) ~ 1e-50).
    unsigned det = 0;
    #pragma unroll
    for (int k = 0; k < 64; ++k) det |= gt_mask[k];
    bool u8 = (det & 0xFFFFFF00u) != 0;
    int valid = u8 ? (((const unsigned char*)gt_mask)[t] != 0)
                   : (gt_mask[t] != 0);

    const float* bx = gt_boxes + t * 4;
    float x1 = bx[0], y1 = bx[1], x2 = bx[2], y2 = bx[3];
    float cx0 = (x1 + x2) * 0.5f, cy0 = (y1 + y2) * 0.5f;
    float w0 = x2 - x1, h0 = y2 - y1;

    const float* anch[3] = { aw_l, aw_m, aw_s };
    const int    Ss[3]   = { 13, 26, 52 };

    // ---- pass 1: best scale via exact max-IoU (separable in x/y) --------
    float best_m = -1.f; int best = 0;
    for (int i = 0; i < 3; ++i) {
        int Si = Ss[i]; float S = (float)Si;
        float stride = RSZ / S;
        float cx = cx0 * S, cy = cy0 * S, w = w0 * S, h = h0 * S;
        float gx1 = cx - w * 0.5f, gy1 = cy - h * 0.5f;
        float gx2 = cx + w * 0.5f, gy2 = cy + h * 0.5f;
        float ag = (gx2 - gx1) * (gy2 - gy1);
        float m = 0.f;
        for (int a = 0; a < 3; ++a) {
            float aw = anch[i][a * 2 + 0] / stride;
            float ah = anch[i][a * 2 + 1] / stride;
            float aw2 = aw * 0.5f, ah2 = ah * 0.5f;
            float aa = aw * ah;
            float mox = 0.f, moy = 0.f;
            for (int c = 0; c < Si; ++c) {
                float ac = c + 0.5f;
                mox = fmaxf(mox, fminf(gx2, ac + aw2) - fmaxf(gx1, ac - aw2));
                moy = fmaxf(moy, fminf(gy2, ac + ah2) - fmaxf(gy1, ac - ah2));
            }
            float inter = mox * moy;
            m = fmaxf(m, inter / (ag + aa - inter));
        }
        if (m > best_m) { best_m = m; best = i; }   // first-max wins
    }

    int cls = gt_labels[t] + 1;
    cls = min(max(cls, 0), NC - 1);

    // ---- pass 2: per-scale record ---------------------------------------
    for (int i = 0; i < 3; ++i) {
        int Si = Ss[i]; float S = (float)Si;
        float stride = RSZ / S;
        float cx = cx0 * S, cy = cy0 * S, w = w0 * S, h = h0 * S;
        float gx1 = cx - w * 0.5f, gy1 = cy - h * 0.5f;
        float gx2 = cx + w * 0.5f, gy2 = cy + h * 0.5f;
        float ag = (gx2 - gx1) * (gy2 - gy1);

        int cellx = (int)floorf(cx); cellx = min(max(cellx, 0), Si - 1);
        int celly = (int)floorf(cy); celly = min(max(celly, 0), Si - 1);
        float acx = cellx + 0.5f, acy = celly + 0.5f;

        float biou = -1.f; int j = 0;
        for (int a = 0; a < 3; ++a) {
            float aw = anch[i][a * 2 + 0] / stride;
            float ah = anch[i][a * 2 + 1] / stride;
            float ox = fmaxf(0.f, fminf(gx2, acx + aw * 0.5f) - fmaxf(gx1, acx - aw * 0.5f));
            float oy = fmaxf(0.f, fminf(gy2, acy + ah * 0.5f) - fmaxf(gy1, acy - ah * 0.5f));
            float inter = ox * oy;
            float iou = inter / (ag + aw * ah - inter);
            if (iou > biou) { biou = iou; j = a; }  // first-max wins
        }

        float tx = cx - floorf(cx), ty = cy - floorf(cy);
        float awj = anch[i][j * 2 + 0] / stride;
        float ahj = anch[i][j * 2 + 1] / stride;
        float tw = logf(w / awj), th = logf(h / ahj);

        int eb = (valid && best == i) ? b : (NB - 1);  // -1 wraps to B-1
        meta[i * NG + t] = cellx | (celly << 6) | (j << 12) | (cls << 14)
                         | (eb << 21) | (valid ? (1 << 26) : 0);
        float* r = rect + (i * NG + t) * 4;
        r[0] = tx; r[1] = ty; r[2] = tw; r[3] = th;
    }
}

// -------------------------------------------------------------------------
// Fused per-scale loss body, ROWS=1 (one cell-anchor row per thread; max
// wave parallelism — the op is latency-bound, occupancy is the lever).
// Invalid GTs are staged as degenerate boxes so the miou loop is branchless
// and unrollable (LDS reads pipeline instead of chaining).
// -------------------------------------------------------------------------
template<int S>
__device__ __forceinline__ float loss_chunk(
    const float* __restrict__ pred, const float* __restrict__ anch,
    const float* __restrict__ gt_boxes,
    const int* __restrict__ ms, const float* __restrict__ rs,
    int b, int chunk,
    float4* s_gb, float* s_ga, int* s_cm)
{
    constexpr int SS3 = S * S * 3;
    const float stride = RSZ / (float)S;

    bool wrapimg = (b == NB - 1);
    int ncand = wrapimg ? NG : NN;
    int cbase = wrapimg ? 0 : b * NN;

    for (int c = threadIdx.x; c < ncand; c += 256) s_cm[c] = ms[cbase + c];
    if (threadIdx.x < NN) {
        int n = threadIdx.x;
        int valid = (ms[b * NN + n] >> 26) & 1;
        const float* bxp = gt_boxes + (b * NN + n) * 4;
        float x1 = bxp[0], y1 = bxp[1], x2 = bxp[2], y2 = bxp[3];
        float Sf = (float)S;
        float cx = (x1 + x2) * 0.5f * Sf, cy = (y1 + y2) * 0.5f * Sf;
        float w = (x2 - x1) * Sf, h = (y2 - y1) * Sf;
        if (valid) {
            float gx1 = cx - w * 0.5f, gy1 = cy - h * 0.5f;
            float gx2 = cx + w * 0.5f, gy2 = cy + h * 0.5f;
            s_gb[n] = make_float4(gx1, gy1, gx2, gy2);
            s_ga[n] = (gx2 - gx1) * (gy2 - gy1);
        } else {
            // degenerate: overlap always 0, area 0 -> iou exactly 0
            s_gb[n] = make_float4(-3e30f, -3e30f, -3e30f, -3e30f);
            s_ga[n] = 0.f;
        }
    }
    __syncthreads();

    int r = chunk * 256 + threadIdx.x;
    if (r >= SS3) return 0.f;

    int j  = r % 3;
    int cx = (r / 3) % S;
    int cy = r / (3 * S);

    float aw = anch[2 * j] / stride, ah = anch[2 * j + 1] / stride;
    float acx = cx + 0.5f, acy = cy + 0.5f;
    float ax1 = acx - aw * 0.5f, ax2 = acx + aw * 0.5f;
    float ay1 = acy - ah * 0.5f, ay2 = acy + ah * 0.5f;
    float aa = aw * ah;

    // issue the obj-logit load early; 86 ch/row, float2-aligned
    const float2* p2 = (const float2*)(pred +
        ((size_t)((b * S + cy) * S + cx)) * (3 * (5 + NC)) + j * (5 + NC));
    float2 v2 = p2[2];               // (obj, cls0)

    // ignore flag: max IoU vs own image's gts — branchless, pipelined
    float miou = 0.f;
    #pragma unroll 4
    for (int n = 0; n < NN; ++n) {
        float4 g = s_gb[n];
        float ox = fmaxf(0.f, fminf(g.z, ax2) - fmaxf(g.x, ax1));
        float oy = fmaxf(0.f, fminf(g.w, ay2) - fmaxf(g.y, ay1));
        float inter = ox * oy;
        miou = fmaxf(miou, inter / (s_ga[n] + aa - inter));
    }

    // scatter-match scan: last match wins for txy/twh; class one-hots union
    unsigned want = (unsigned)(cx | (cy << 6) | (j << 12) | (b << 21));
    const unsigned MASK = 0x3FFFu | (31u << 21);
    int win = -1;
    unsigned cb0 = 0u, cb1 = 0u, cb2 = 0u;
    #pragma unroll 4
    for (int c = 0; c < ncand; ++c) {
        int m = s_cm[c];
        if (((unsigned)m & MASK) == want) {
            win = c;
            int cl = (m >> 14) & 127;
            unsigned bit = 1u << (cl & 31);
            cb0 |= (cl < 32) ? bit : 0u;
            cb1 |= (cl >= 32 && cl < 64) ? bit : 0u;
            cb2 |= (cl >= 64) ? bit : 0u;
        }
    }

    float pobj = v2.x;
    if (win >= 0) {
        float4 tr = *(const float4*)(rs + (size_t)(cbase + win) * 4);
        float2 v0 = p2[0], v1 = p2[1];
        float sx = 1.f / (1.f + expf(-v0.x));
        float sy = 1.f / (1.f + expf(-v0.y));
        float dx = sx - tr.x, dy = sy - tr.y;
        float dw = v1.x - tr.z, dh = v1.y - tr.w;
        float xy_l  = 0.5f * (dx * dx + dy * dy);
        float wh_l  = 0.5f * (dw * dw + dh * dh);
        float obj_l = softplusf(-pobj);
        float cls_l = (cb0 & 1u) ? softplusf(-v2.y) : softplusf(v2.y);
        #pragma unroll 8
        for (int q = 3; q < 43; ++q) {
            float2 v = p2[q];
            int c0 = 2 * q - 5, c1 = 2 * q - 4;
            cls_l += getbit(c0, cb0, cb1, cb2) ? softplusf(-v.x) : softplusf(v.x);
            cls_l += getbit(c1, cb0, cb1, cb2) ? softplusf(-v.y) : softplusf(v.y);
        }
        return (5.f * (xy_l + wh_l) + obj_l + cls_l) * (1.f / NB);
    } else {
        float ignore = (miou < 0.5f) ? 1.f : 0.f;
        return 0.5f * ignore * softplusf(pobj) * (1.f / NB);
    }
}

// -------------------------------------------------------------------------
// Fused loss kernel: all 3 scales, one launch, per-block partial stores.
// -------------------------------------------------------------------------
__global__ __launch_bounds__(256) void yolo_loss_all(
    const float* __restrict__ pred13, const float* __restrict__ pred26,
    const float* __restrict__ pred52, const float* __restrict__ gt_boxes,
    const float* __restrict__ aw_l, const float* __restrict__ aw_m,
    const float* __restrict__ aw_s,
    const int* __restrict__ meta, const float* __restrict__ rect,
    float* __restrict__ partial)
{
    __shared__ float4 s_gb[NN];
    __shared__ float  s_ga[NN];
    __shared__ int    s_cm[NG];
    __shared__ float  s_red[256];

    int bx = blockIdx.x;
    float acc;
    if (bx < 64) {
        acc = loss_chunk<13>(pred13, aw_l, gt_boxes, meta, rect,
                             bx >> 1, bx & 1, s_gb, s_ga, s_cm);
    } else if (bx < 320) {
        int l = bx - 64;
        acc = loss_chunk<26>(pred26, aw_m, gt_boxes, meta + NG,
                             rect + (size_t)NG * 4,
                             l >> 3, l & 7, s_gb, s_ga, s_cm);
    } else {
        int l = bx - 320;
        acc = loss_chunk<52>(pred52, aw_s, gt_boxes, meta + 2 * NG,
                             rect + (size_t)2 * NG * 4,
                             l >> 5, l & 31, s_gb, s_ga, s_cm);
    }

    s_red[threadIdx.x] = acc;
    __syncthreads();
    for (int o = 128; o > 0; o >>= 1) {
        if (threadIdx.x < o) s_red[threadIdx.x] += s_red[threadIdx.x + o];
        __syncthreads();
    }
    if (threadIdx.x == 0) partial[bx] = s_red[0];
}

__global__ __launch_bounds__(256) void yolo_finalize(
    const float* __restrict__ partial, float* __restrict__ out)
{
    __shared__ float s[256];
    float a = 0.f;
    for (int i = threadIdx.x; i < NPART; i += 256) a += partial[i];
    s[threadIdx.x] = a;
    __syncthreads();
    for (int o = 128; o > 0; o >>= 1) {
        if (threadIdx.x < o) s[threadIdx.x] += s[threadIdx.x + o];
        __syncthreads();
    }
    if (threadIdx.x == 0) out[0] = s[0];
}

extern "C" void kernel_launch(void* const* d_in, const int* in_sizes, int n_in,
                              void* d_out, int out_size, void* d_ws, size_t ws_size,
                              hipStream_t stream)
{
    const float*    pred_l    = (const float*)d_in[0];   // S=13
    const float*    pred_m    = (const float*)d_in[1];   // S=26
    const float*    pred_s    = (const float*)d_in[2];   // S=52
    const float*    gt_boxes  = (const float*)d_in[3];
    const int*      gt_labels = (const int*)d_in[4];
    const unsigned* gt_mask   = (const unsigned*)d_in[5];
    const float*    aw_l      = (const float*)d_in[6];
    const float*    aw_m      = (const float*)d_in[7];
    const float*    aw_s      = (const float*)d_in[8];

    int*   meta    = (int*)d_ws;                                        // 3*NG ints
    float* rect    = (float*)((char*)d_ws + 3 * NG * sizeof(int));      // 3*NG*4 f32 (16B-aligned)
    float* partial = (float*)((char*)d_ws + 3 * NG * sizeof(int)
                                          + 3 * NG * 4 * sizeof(float)); // NPART f32

    yolo_assign<<<dim3((NG + 255) / 256), 256, 0, stream>>>(
        gt_boxes, gt_labels, gt_mask, aw_l, aw_m, aw_s, meta, rect);

    yolo_loss_all<<<dim3(NPART), 256, 0, stream>>>(
        pred_l, pred_m, pred_s, gt_boxes, aw_l, aw_m, aw_s, meta, rect, partial);

    yolo_finalize<<<dim3(1), 256, 0, stream>>>(partial, (float*)d_out);
}